// Round 10
// baseline (1738.273 us; speedup 1.0000x reference)
//
#include <hip/hip_runtime.h>
#include <hip/hip_bf16.h>

#define NATOM 100000
#define MNBR  12
#define FDIM  64
#define BDIM  41
#define C2    128
#define EPSBN 1e-5f
#define NEDGE (NATOM * MNBR)   // 1,200,000
#define KP48  48               // nbr packed width (41 real + 7 zero)
#define NFRAG  16384           // edge B frag-linear: 8T * 4s * 64l * 8e (rows 64..168)
#define NFRAGS 8192            // self B frag-linear: 8T * 2s * 64l * 8e (rows 0..63)

typedef __attribute__((ext_vector_type(8))) short bf16x8;
typedef __attribute__((ext_vector_type(4))) float f32x4;

// ---- ws layout (float units) ----
#define X_OFF    0L            // x: N*64 f32 (master)
#define XB_OFF   6400000L      // xb: N*64 bf16
#define S_OFF    9600000L      // nbr_sumed: N*64 f32
#define NBRB_OFF 16000000L     // nbr bf16 packed 48-wide: 1.2M*48 bf16 (28.8M floats)
#define AS_OFF   54400000L     // a = x@W_self: N*128 bf16 (6.4M floats)
#define BALL_OFF 60800000L     // edge B frag bf16: 16384 elems (8192 floats)
#define BALLS_OFF 60808192L    // self B frag bf16: 8192 elems (4096 floats)
#define BN1S_OFF 60812288L     // 64 slots * 256
#define BN2S_OFF 60828672L     // 64 slots * 128
#define SC1_OFF  60836864L
#define SH1_OFF  60836992L
#define SC2_OFF  60837120L
#define SH2_OFF  60837184L
#define CRY_OFF  60837248L     // 2000*64
#define CNT_OFF  60965248L     // 2000
#define ZERO_OFF BN1S_OFF
#define ZERO_CNT 154960L

__device__ __forceinline__ float bf2f(unsigned short u) {
    return __uint_as_float(((unsigned)u) << 16);
}
__device__ __forceinline__ float softplus_f(float v) {
    return fmaxf(v, 0.f) + __logf(1.f + __expf(-fabsf(v)));
}

__global__ void k_zero(float* __restrict__ p, long cnt) {
    long i = (long)blockIdx.x * 256 + threadIdx.x;
    if (i < cnt) p[i] = 0.f;
}

// nbr_fea f32 [1.2M][41] -> bf16 [1.2M][48] zero-padded (96B rows)
__global__ void k_nbrcvt(const float* __restrict__ nbr, __hip_bfloat16* __restrict__ outb) {
    long i = (long)blockIdx.x * 256 + threadIdx.x;
    if (i >= (long)NEDGE * KP48) return;
    long e = i / KP48;
    int k = (int)(i - e * KP48);
    float v = (k < BDIM) ? nbr[e * BDIM + k] : 0.f;
    outb[i] = __float2bfloat16(v);
}

// Fragment-linear B for both GEMMs.
// edge  (K=128, W rows 64..168): ballf [((T*4+s)*64+l)*8+e] = W[64+s*32+(l>>4)*8+e][T*16+(l&15)]
// self  (K=64,  W rows  0..63 ): ballfS[((T*2+s)*64+l)*8+e] = W[   s*32+(l>>4)*8+e][T*16+(l&15)]
__global__ void k_bcvt(const float* __restrict__ cw, __hip_bfloat16* __restrict__ ballf,
                       __hip_bfloat16* __restrict__ ballfS) {
    int i = blockIdx.x * 256 + threadIdx.x;
    if (i < NFRAG) {
        int T = i / 2048, r = i - T * 2048;
        int lidx = (r >> 3) & 63, e = i & 7;
        int s4 = r >> 9;
        int lo = lidx & 15, hi = lidx >> 4;
        int krow = 64 + s4 * 32 + hi * 8 + e;
        float v = (krow < 169) ? cw[krow * C2 + T * 16 + lo] : 0.f;
        ballf[i] = __float2bfloat16(v);
    } else if (i < NFRAG + NFRAGS) {
        int i2 = i - NFRAG;
        int T = i2 / 1024, r = i2 - T * 1024;
        int lidx = (r >> 3) & 63, e = i2 & 7;
        int s = r >> 9;
        int lo = lidx & 15, hi = lidx >> 4;
        int krow = s * 32 + hi * 8 + e;   // 0..63
        ballfS[i2] = __float2bfloat16(cw[krow * C2 + T * 16 + lo]);
    }
}

__global__ __launch_bounds__(256)
void k_embed(const float* __restrict__ af, const float* __restrict__ ew,
             const float* __restrict__ eb, float* __restrict__ x,
             __hip_bfloat16* __restrict__ xb) {
    int t = threadIdx.x;
    int c = t & 63, ag = t >> 6;
    long n0 = (long)blockIdx.x * 16 + ag * 4;
    float acc[4] = {0.f, 0.f, 0.f, 0.f};
    for (int k4 = 0; k4 < 23; ++k4) {
        float w0 = ew[(4 * k4 + 0) * FDIM + c];
        float w1 = ew[(4 * k4 + 1) * FDIM + c];
        float w2 = ew[(4 * k4 + 2) * FDIM + c];
        float w3 = ew[(4 * k4 + 3) * FDIM + c];
#pragma unroll
        for (int a = 0; a < 4; ++a) {
            const float4* ar = (const float4*)(af + (n0 + a) * 92);
            float4 v = ar[k4];
            acc[a] += v.x * w0 + v.y * w1 + v.z * w2 + v.w * w3;
        }
    }
    float b = eb[c];
#pragma unroll
    for (int a = 0; a < 4; ++a) {
        float v = acc[a] + b;
        x[(n0 + a) * FDIM + c] = v;
        xb[(n0 + a) * FDIM + c] = __float2bfloat16(v);
    }
}

// aS = xb @ W_self via MFMA: one 16-atom tile per wave (A rows = atoms).
__global__ __launch_bounds__(256)
void k_lin(const __hip_bfloat16* __restrict__ xb, const __hip_bfloat16* __restrict__ ballfS,
           __hip_bfloat16* __restrict__ aS) {
    int t = threadIdx.x, w = t >> 6, l = t & 63;
    int lo = l & 15, hi = l >> 4;
    long atom0 = ((long)blockIdx.x * 4 + w) * 16;
    if (atom0 >= NATOM) return;
    const short* xs = (const short*)xb + (atom0 + lo) * FDIM + hi * 8;
    bf16x8 A0 = *(const bf16x8*)(xs);
    bf16x8 A1 = *(const bf16x8*)(xs + 32);
    const short* bS = (const short*)ballfS;
#pragma unroll
    for (int T = 0; T < 8; ++T) {
        bf16x8 B0 = *(const bf16x8*)(bS + T * 1024 + l * 8);
        bf16x8 B1 = *(const bf16x8*)(bS + T * 1024 + 512 + l * 8);
        f32x4 z = {0.f, 0.f, 0.f, 0.f};
        z = __builtin_amdgcn_mfma_f32_16x16x32_bf16(A0, B0, z, 0, 0, 0);
        z = __builtin_amdgcn_mfma_f32_16x16x32_bf16(A1, B1, z, 0, 0, 0);
#pragma unroll
        for (int qq = 0; qq < 4; ++qq)
            aS[(atom0 + hi * 4 + qq) * C2 + T * 16 + lo] = __float2bfloat16(z[qq]);
    }
}

// Edge kernel v10: 4 atoms/wave, A[4][4] held in regs across the fully-unrolled
// P loop; each B fragment read ONCE per wave per P-round and feeds all 4 atoms
// (B traffic/wave halved vs r8). Stats epilogue accumulates in registers
// (racc[8]); shfl+LDS-atomics only at kernel end (4x fewer DS ops).
// nbr packed 48-wide: slice-1 frags for k>=48 are compile-time zero.
// APPLY=0: BN1 column stats. APPLY=1: BN1 apply + sig*softplus + m-sum + BN2 stats.
template <int APPLY>
__global__ __launch_bounds__(256, 3)
void k_edge(const __hip_bfloat16* __restrict__ xb,
            const __hip_bfloat16* __restrict__ nbrb,
            const __hip_bfloat16* __restrict__ ballf,
            const __hip_bfloat16* __restrict__ aS,
            const int* __restrict__ idxp,
            const float* __restrict__ sc1, const float* __restrict__ sh1,
            float* __restrict__ bn1_slots,
            float* __restrict__ sout, float* __restrict__ bn2_slots) {
    __shared__ float bn_s[256];
    __shared__ float sc_s[128], sh_s[128];

    const int t = threadIdx.x;
    const int w = t >> 6, l = t & 63;
    const int lo = l & 15, hi = l >> 4;
    const bool real = lo < MNBR;
    const int elo = real ? lo : 0;           // clamp pad A-rows in-bounds
    const int atom0 = blockIdx.x * 16 + w * 4;
    const short* xbS = (const short*)xb;
    const short* nbS = (const short*)nbrb;
    const short* aSS = (const short*)aS;
    const short* bb  = (const short*)ballf;

    bn_s[t] = 0.f;
    if (APPLY && t < 128) { sc_s[t] = sc1[t]; sh_s[t] = sh1[t]; }
    __syncthreads();

    // ---- load all A fragments: 4 atoms x 4 k-slices, held across the P loop ----
    bf16x8 A[4][4];
    {
        bf16x8 zz = {0, 0, 0, 0, 0, 0, 0, 0};
#pragma unroll
        for (int a = 0; a < 4; ++a) {
            const int j = idxp[(long)(atom0 + a) * MNBR + elo];
            const short* xj_ = xbS + (long)j * FDIM + hi * 8;
            const short* nb_ = nbS + ((long)(atom0 + a) * MNBR + elo) * KP48;
            A[a][0] = *(const bf16x8*)(xj_);
            A[a][1] = *(const bf16x8*)(xj_ + 32);
            A[a][2] = *(const bf16x8*)(nb_ + hi * 8);
            const int off1 = (hi < 2) ? (32 + hi * 8) : 0;
            bf16x8 n1 = *(const bf16x8*)(nb_ + off1);
            A[a][3] = (hi < 2) ? n1 : zz;
        }
    }

    if (APPLY == 0) {
        float racc1[8], racc2[8];
#pragma unroll
        for (int P = 0; P < 8; ++P) { racc1[P] = 0.f; racc2[P] = 0.f; }
#pragma unroll
        for (int P = 0; P < 8; ++P) {
            const short* bp = bb + P * 2048 + l * 8;
            bf16x8 B0 = *(const bf16x8*)(bp);
            bf16x8 B1 = *(const bf16x8*)(bp + 512);
            bf16x8 B2 = *(const bf16x8*)(bp + 1024);
            bf16x8 B3 = *(const bf16x8*)(bp + 1536);
#pragma unroll
            for (int a = 0; a < 4; ++a) {
                f32x4 z = {0.f, 0.f, 0.f, 0.f};
                z = __builtin_amdgcn_mfma_f32_16x16x32_bf16(A[a][0], B0, z, 0, 0, 0);
                z = __builtin_amdgcn_mfma_f32_16x16x32_bf16(A[a][1], B1, z, 0, 0, 0);
                z = __builtin_amdgcn_mfma_f32_16x16x32_bf16(A[a][2], B2, z, 0, 0, 0);
                z = __builtin_amdgcn_mfma_f32_16x16x32_bf16(A[a][3], B3, z, 0, 0, 0);
                float av = bf2f((unsigned short)aSS[(long)(atom0 + a) * C2 + P * 16 + lo]);
                float sz = z[0] + z[1] + z[2] + z[3];
                float szz = z[0] * z[0] + z[1] * z[1] + z[2] * z[2] + z[3] * z[3];
                float s1 = sz + 4.f * av;
                float s2 = szz + 2.f * av * sz + 4.f * av * av;
                if (hi == 3) { s1 = 0.f; s2 = 0.f; }   // mask pad output rows
                racc1[P] += s1;
                racc2[P] += s2;
            }
        }
        // final reduce: butterfly across hi-groups, one atomic pair per P
#pragma unroll
        for (int P = 0; P < 8; ++P) {
            float r1 = racc1[P], r2 = racc2[P];
            r1 += __shfl_xor(r1, 16); r2 += __shfl_xor(r2, 16);
            r1 += __shfl_xor(r1, 32); r2 += __shfl_xor(r2, 32);
            if (hi == 0) {
                atomicAdd(&bn_s[P * 16 + lo], r1);
                atomicAdd(&bn_s[128 + P * 16 + lo], r2);
            }
        }
        __syncthreads();
        atomicAdd(&bn1_slots[(blockIdx.x & 63) * 256 + t], bn_s[t]);
    } else {
        float racca[4], raccb[4];
#pragma unroll
        for (int P = 0; P < 4; ++P) { racca[P] = 0.f; raccb[P] = 0.f; }
#pragma unroll
        for (int P = 0; P < 4; ++P) {
            const short* bpf = bb + P * 2048 + l * 8;
            const short* bpc = bb + (P + 4) * 2048 + l * 8;
            bf16x8 Bf0 = *(const bf16x8*)(bpf);
            bf16x8 Bf1 = *(const bf16x8*)(bpf + 512);
            bf16x8 Bf2 = *(const bf16x8*)(bpf + 1024);
            bf16x8 Bf3 = *(const bf16x8*)(bpf + 1536);
            bf16x8 Bc0 = *(const bf16x8*)(bpc);
            bf16x8 Bc1 = *(const bf16x8*)(bpc + 512);
            bf16x8 Bc2 = *(const bf16x8*)(bpc + 1024);
            bf16x8 Bc3 = *(const bf16x8*)(bpc + 1536);
            const int c = P * 16 + lo;
            const float s_f = sc_s[c], h_f = sh_s[c];
            const float s_c = sc_s[64 + c], h_c = sh_s[64 + c];
#pragma unroll
            for (int a = 0; a < 4; ++a) {
                f32x4 zf = {0.f, 0.f, 0.f, 0.f}, zc = {0.f, 0.f, 0.f, 0.f};
                zf = __builtin_amdgcn_mfma_f32_16x16x32_bf16(A[a][0], Bf0, zf, 0, 0, 0);
                zc = __builtin_amdgcn_mfma_f32_16x16x32_bf16(A[a][0], Bc0, zc, 0, 0, 0);
                zf = __builtin_amdgcn_mfma_f32_16x16x32_bf16(A[a][1], Bf1, zf, 0, 0, 0);
                zc = __builtin_amdgcn_mfma_f32_16x16x32_bf16(A[a][1], Bc1, zc, 0, 0, 0);
                zf = __builtin_amdgcn_mfma_f32_16x16x32_bf16(A[a][2], Bf2, zf, 0, 0, 0);
                zc = __builtin_amdgcn_mfma_f32_16x16x32_bf16(A[a][2], Bc2, zc, 0, 0, 0);
                zf = __builtin_amdgcn_mfma_f32_16x16x32_bf16(A[a][3], Bf3, zf, 0, 0, 0);
                zc = __builtin_amdgcn_mfma_f32_16x16x32_bf16(A[a][3], Bc3, zc, 0, 0, 0);
                float hvf = bf2f((unsigned short)aSS[(long)(atom0 + a) * C2 + c]) * s_f + h_f;
                float hvc = bf2f((unsigned short)aSS[(long)(atom0 + a) * C2 + 64 + c]) * s_c + h_c;
                float pvsum = 0.f;
#pragma unroll
                for (int qq = 0; qq < 4; ++qq) {
                    float zfh = zf[qq] * s_f + hvf;
                    float zch = zc[qq] * s_c + hvc;
                    float filt = 1.f / (1.f + __expf(-zfh));
                    pvsum += filt * softplus_f(zch);
                }
                if (hi == 3) pvsum = 0.f;   // mask pad output rows
                pvsum += __shfl_xor(pvsum, 16);
                pvsum += __shfl_xor(pvsum, 32);
                if (hi == 0) sout[(long)(atom0 + a) * FDIM + c] = pvsum;
                racca[P] += pvsum;            // replicated across lanes post-butterfly
                raccb[P] += pvsum * pvsum;
            }
        }
#pragma unroll
        for (int P = 0; P < 4; ++P) {
            if (hi == 0) {
                atomicAdd(&bn_s[P * 16 + lo], racca[P]);
                atomicAdd(&bn_s[64 + P * 16 + lo], raccb[P]);
            }
        }
        __syncthreads();
        if (t < 128)
            atomicAdd(&bn2_slots[(blockIdx.x & 63) * 128 + t], bn_s[t]);
    }
}

// reduce 64 slots -> scale/shift; zero slots for next layer.
// Linear bias is a no-op under training-mode BN -> no bias anywhere.
__global__ void k_bnfin(float* __restrict__ slots, const float* __restrict__ gamma,
                        const float* __restrict__ beta,
                        float* __restrict__ scale, float* __restrict__ shift,
                        float inv_cnt, int nc) {
    int c = threadIdx.x;
    if (c >= nc) return;
    float s1 = 0.f, s2 = 0.f;
    for (int s = 0; s < 64; ++s) {
        s1 += slots[s * 2 * nc + c];
        s2 += slots[s * 2 * nc + nc + c];
    }
    for (int s = 0; s < 64; ++s) {
        slots[s * 2 * nc + c] = 0.f;
        slots[s * 2 * nc + nc + c] = 0.f;
    }
    float mu = s1 * inv_cnt;
    float var = fmaxf(s2 * inv_cnt - mu * mu, 0.f);
    float sc = gamma[c] * rsqrtf(var + EPSBN);
    scale[c] = sc;
    shift[c] = beta[c] - mu * sc;
}

// x = softplus(x + bn2(s)); also refresh xb
__global__ void k_x(float* __restrict__ x, __hip_bfloat16* __restrict__ xb,
                    const float* __restrict__ s,
                    const float* __restrict__ scale2, const float* __restrict__ shift2) {
    long i = (long)blockIdx.x * 256 + threadIdx.x;
    if (i >= (long)NATOM * FDIM) return;
    int c = (int)(i & 63);
    float v = softplus_f(x[i] + s[i] * scale2[c] + shift2[c]);
    x[i] = v;
    xb[i] = __float2bfloat16(v);
}

__global__ void k_pool(const float* __restrict__ x, const int* __restrict__ seg,
                       float* __restrict__ cry, float* __restrict__ cnt) {
    long i = (long)blockIdx.x * 256 + threadIdx.x;
    if (i >= (long)NATOM * FDIM) return;
    int n = (int)(i >> 6), c = (int)(i & 63);
    int cr = seg[n];
    atomicAdd(&cry[(long)cr * FDIM + c], x[i]);
    if (c == 0) atomicAdd(&cnt[cr], 1.f);
}

__global__ __launch_bounds__(256)
void k_head(const float* __restrict__ cry, const float* __restrict__ cnt,
            const float* __restrict__ fw, const float* __restrict__ fb,
            const float* __restrict__ hw, const float* __restrict__ hb,
            const float* __restrict__ ow, const float* __restrict__ ob,
            float* __restrict__ out) {
    __shared__ float cs[64], h1[128], red[256];
    int t = threadIdx.x, cr = blockIdx.x;
    if (t < 64) cs[t] = cry[(long)cr * 64 + t] / fmaxf(cnt[cr], 1.f);
    __syncthreads();
    if (t < 128) {
        float a = fb[t];
        for (int k = 0; k < 64; ++k) a += cs[k] * fw[k * 128 + t];
        h1[t] = fmaxf(a, 0.f);
    }
    __syncthreads();
    float a = hb[t];
    for (int k = 0; k < 128; ++k) a += h1[k] * hw[k * 256 + t];
    red[t] = a * ow[t];
    __syncthreads();
    for (int off = 128; off > 0; off >>= 1) {
        if (t < off) red[t] += red[t + off];
        __syncthreads();
    }
    if (t == 0) out[cr] = red[0] + ob[0];
}

extern "C" void kernel_launch(void* const* d_in, const int* in_sizes, int n_in,
                              void* d_out, int out_size, void* d_ws, size_t ws_size,
                              hipStream_t stream) {
    const float* atom_fea = (const float*)d_in[0];
    const float* nbr_fea  = (const float*)d_in[1];
    const int*   nbr_idx  = (const int*)d_in[2];
    const int*   seg      = (const int*)d_in[3];
    const float* emb_w    = (const float*)d_in[4];
    const float* emb_b    = (const float*)d_in[5];
    const float* conv_w   = (const float*)d_in[6];
    const float* bn1_g    = (const float*)d_in[8];
    const float* bn1_b    = (const float*)d_in[9];
    const float* bn2_g    = (const float*)d_in[10];
    const float* bn2_b    = (const float*)d_in[11];
    const float* fc_w     = (const float*)d_in[12];
    const float* fc_b     = (const float*)d_in[13];
    const float* head_w   = (const float*)d_in[14];
    const float* head_b   = (const float*)d_in[15];
    const float* out_w    = (const float*)d_in[16];
    const float* out_b    = (const float*)d_in[17];
    float* out = (float*)d_out;

    float* ws = (float*)d_ws;
    float* x = ws + X_OFF;
    __hip_bfloat16* xb     = (__hip_bfloat16*)(ws + XB_OFF);
    float* s = ws + S_OFF;
    __hip_bfloat16* nbrb   = (__hip_bfloat16*)(ws + NBRB_OFF);
    __hip_bfloat16* aS     = (__hip_bfloat16*)(ws + AS_OFF);
    __hip_bfloat16* ballf  = (__hip_bfloat16*)(ws + BALL_OFF);
    __hip_bfloat16* ballfS = (__hip_bfloat16*)(ws + BALLS_OFF);
    float* bn1s = ws + BN1S_OFF;
    float* bn2s = ws + BN2S_OFF;
    float* sc1 = ws + SC1_OFF;
    float* sh1 = ws + SH1_OFF;
    float* sc2 = ws + SC2_OFF;
    float* sh2 = ws + SH2_OFF;
    float* cry = ws + CRY_OFF;
    float* cnt = ws + CNT_OFF;

    k_zero<<<(int)((ZERO_CNT + 255) / 256), 256, 0, stream>>>(ws + ZERO_OFF, ZERO_CNT);
    k_nbrcvt<<<(int)(((long)NEDGE * KP48 + 255) / 256), 256, 0, stream>>>(nbr_fea, nbrb);
    k_embed<<<NATOM / 16, 256, 0, stream>>>(atom_fea, emb_w, emb_b, x, xb);

    for (int i = 0; i < 3; ++i) {
        const float* cw = conv_w + (long)i * 169 * C2;
        k_bcvt<<<96, 256, 0, stream>>>(cw, ballf, ballfS);
        k_lin<<<1563, 256, 0, stream>>>(xb, ballfS, aS);
        k_edge<0><<<NATOM / 16, 256, 0, stream>>>(xb, nbrb, ballf, aS, nbr_idx,
                                                  nullptr, nullptr, bn1s, nullptr, nullptr);
        k_bnfin<<<1, 128, 0, stream>>>(bn1s, bn1_g + i * C2, bn1_b + i * C2,
                                       sc1, sh1, 1.f / 1200000.f, 128);
        k_edge<1><<<NATOM / 16, 256, 0, stream>>>(xb, nbrb, ballf, aS, nbr_idx,
                                                  sc1, sh1, nullptr, s, bn2s);
        k_bnfin<<<1, 64, 0, stream>>>(bn2s, bn2_g + i * 64, bn2_b + i * 64,
                                      sc2, sh2, 1e-5f, 64);
        k_x<<<(NATOM * FDIM) / 256, 256, 0, stream>>>(x, xb, s, sc2, sh2);
    }

    k_pool<<<(NATOM * FDIM) / 256, 256, 0, stream>>>(x, seg, cry, cnt);
    k_head<<<2000, 256, 0, stream>>>(cry, cnt, fc_w, fc_b, head_w, head_b, out_w, out_b, out);
}

// Round 11
// 1363.804 us; speedup vs baseline: 1.2746x; 1.2746x over previous
//
#include <hip/hip_runtime.h>
#include <hip/hip_bf16.h>

#define NATOM 100000
#define MNBR  12
#define FDIM  64
#define BDIM  41
#define C2    128
#define EPSBN 1e-5f
#define NEDGE (NATOM * MNBR)   // 1,200,000
#define KP48  48               // nbr packed width (41 real + 7 zero), 96B rows
#define NFRAG  16384           // edge B frag-linear: 8T * 4s * 64l * 8e (rows 64..168)
#define NFRAGS 8192            // self B frag-linear: 8T * 2s * 64l * 8e (rows 0..63)

typedef __attribute__((ext_vector_type(8))) short bf16x8;
typedef __attribute__((ext_vector_type(4))) float f32x4;

// ---- ws layout (float units) ----
#define X_OFF    0L            // x: N*64 f32 (master)
#define XB_OFF   6400000L      // xb: N*64 bf16
#define S_OFF    9600000L      // nbr_sumed: N*64 f32
#define NBRB_OFF 16000000L     // nbr bf16 packed 48-wide: 1.2M*48 bf16 (28.8M floats)
#define AS_OFF   54400000L     // a = x@W_self: N*128 bf16 (6.4M floats)
#define BALL_OFF 60800000L     // edge B frag bf16: 16384 elems (8192 floats)
#define BALLS_OFF 60808192L    // self B frag bf16: 8192 elems (4096 floats)
#define BN1S_OFF 60812288L     // 64 slots * 256
#define BN2S_OFF 60828672L     // 64 slots * 128
#define SC1_OFF  60836864L
#define SH1_OFF  60836992L
#define SC2_OFF  60837120L
#define SH2_OFF  60837184L
#define CRY_OFF  60837248L     // 2000*64
#define CNT_OFF  60965248L     // 2000
#define ZERO_OFF BN1S_OFF
#define ZERO_CNT 154960L

__device__ __forceinline__ float bf2f(unsigned short u) {
    return __uint_as_float(((unsigned)u) << 16);
}
__device__ __forceinline__ float softplus_f(float v) {
    return fmaxf(v, 0.f) + __logf(1.f + __expf(-fabsf(v)));
}

__global__ void k_zero(float* __restrict__ p, long cnt) {
    long i = (long)blockIdx.x * 256 + threadIdx.x;
    if (i < cnt) p[i] = 0.f;
}

// nbr_fea f32 [1.2M][41] -> bf16 [1.2M][48] zero-padded; short8-vectorized writes
__global__ void k_nbrcvt(const float* __restrict__ nbr, __hip_bfloat16* __restrict__ outb) {
    long i = (long)blockIdx.x * 256 + threadIdx.x;   // one 8-elem chunk each
    if (i >= (long)NEDGE * 6) return;
    long e = i / 6;
    int c = (int)(i - e * 6);
    const float* src = nbr + e * BDIM + c * 8;
    bf16x8 v;
#pragma unroll
    for (int j = 0; j < 8; ++j) {
        int k = c * 8 + j;
        float f = (k < BDIM) ? src[j] : 0.f;
        v[j] = (short)(__float_as_uint(f) >> 16);   // quick rne-less cvt? no: use proper
    }
    // proper bf16 conversion (round-to-nearest-even)
#pragma unroll
    for (int j = 0; j < 8; ++j) {
        int k = c * 8 + j;
        float f = (k < BDIM) ? src[j] : 0.f;
        __hip_bfloat16 h = __float2bfloat16(f);
        v[j] = *(short*)&h;
    }
    *(bf16x8*)((short*)outb + e * KP48 + c * 8) = v;
}

// Fragment-linear B for both GEMMs.
// edge  (K=128, W rows 64..168): ballf [((T*4+s)*64+l)*8+e] = W[64+s*32+(l>>4)*8+e][T*16+(l&15)]
// self  (K=64,  W rows  0..63 ): ballfS[((T*2+s)*64+l)*8+e] = W[   s*32+(l>>4)*8+e][T*16+(l&15)]
__global__ void k_bcvt(const float* __restrict__ cw, __hip_bfloat16* __restrict__ ballf,
                       __hip_bfloat16* __restrict__ ballfS) {
    int i = blockIdx.x * 256 + threadIdx.x;
    if (i < NFRAG) {
        int T = i / 2048, r = i - T * 2048;
        int lidx = (r >> 3) & 63, e = i & 7;
        int s4 = r >> 9;
        int lo = lidx & 15, hi = lidx >> 4;
        int krow = 64 + s4 * 32 + hi * 8 + e;
        float v = (krow < 169) ? cw[krow * C2 + T * 16 + lo] : 0.f;
        ballf[i] = __float2bfloat16(v);
    } else if (i < NFRAG + NFRAGS) {
        int i2 = i - NFRAG;
        int T = i2 / 1024, r = i2 - T * 1024;
        int lidx = (r >> 3) & 63, e = i2 & 7;
        int s = r >> 9;
        int lo = lidx & 15, hi = lidx >> 4;
        int krow = s * 32 + hi * 8 + e;   // 0..63
        ballfS[i2] = __float2bfloat16(cw[krow * C2 + T * 16 + lo]);
    }
}

__global__ __launch_bounds__(256)
void k_embed(const float* __restrict__ af, const float* __restrict__ ew,
             const float* __restrict__ eb, float* __restrict__ x,
             __hip_bfloat16* __restrict__ xb) {
    int t = threadIdx.x;
    int c = t & 63, ag = t >> 6;
    long n0 = (long)blockIdx.x * 16 + ag * 4;
    float acc[4] = {0.f, 0.f, 0.f, 0.f};
    for (int k4 = 0; k4 < 23; ++k4) {
        float w0 = ew[(4 * k4 + 0) * FDIM + c];
        float w1 = ew[(4 * k4 + 1) * FDIM + c];
        float w2 = ew[(4 * k4 + 2) * FDIM + c];
        float w3 = ew[(4 * k4 + 3) * FDIM + c];
#pragma unroll
        for (int a = 0; a < 4; ++a) {
            const float4* ar = (const float4*)(af + (n0 + a) * 92);
            float4 v = ar[k4];
            acc[a] += v.x * w0 + v.y * w1 + v.z * w2 + v.w * w3;
        }
    }
    float b = eb[c];
#pragma unroll
    for (int a = 0; a < 4; ++a) {
        float v = acc[a] + b;
        x[(n0 + a) * FDIM + c] = v;
        xb[(n0 + a) * FDIM + c] = __float2bfloat16(v);
    }
}

// aS = xb @ W_self via MFMA: one 16-atom tile per wave (A rows = atoms).
__global__ __launch_bounds__(256)
void k_lin(const __hip_bfloat16* __restrict__ xb, const __hip_bfloat16* __restrict__ ballfS,
           __hip_bfloat16* __restrict__ aS) {
    int t = threadIdx.x, w = t >> 6, l = t & 63;
    int lo = l & 15, hi = l >> 4;
    long atom0 = ((long)blockIdx.x * 4 + w) * 16;
    if (atom0 >= NATOM) return;
    const short* xs = (const short*)xb + (atom0 + lo) * FDIM + hi * 8;
    bf16x8 A0 = *(const bf16x8*)(xs);
    bf16x8 A1 = *(const bf16x8*)(xs + 32);
    const short* bS = (const short*)ballfS;
#pragma unroll
    for (int T = 0; T < 8; ++T) {
        bf16x8 B0 = *(const bf16x8*)(bS + T * 1024 + l * 8);
        bf16x8 B1 = *(const bf16x8*)(bS + T * 1024 + 512 + l * 8);
        f32x4 z = {0.f, 0.f, 0.f, 0.f};
        z = __builtin_amdgcn_mfma_f32_16x16x32_bf16(A0, B0, z, 0, 0, 0);
        z = __builtin_amdgcn_mfma_f32_16x16x32_bf16(A1, B1, z, 0, 0, 0);
#pragma unroll
        for (int qq = 0; qq < 4; ++qq)
            aS[(atom0 + hi * 4 + qq) * C2 + T * 16 + lo] = __float2bfloat16(z[qq]);
    }
}

// Edge kernel (r8 structure + 48-wide nbr): one atom per 16x16 MFMA tile
// (12 real rows + 4 pads, masked), K=128 ([x[j] | nbr48]); self term folded
// into epilogue; B straight from global (L1/L2-hot); 2-atom pairs keep A
// live-range at 32 VGPR. Block: 256 threads = 4 waves * 4 atoms = 16 atoms.
template <int APPLY>
__global__ __launch_bounds__(256, 4)
void k_edge(const __hip_bfloat16* __restrict__ xb,
            const __hip_bfloat16* __restrict__ nbrb,
            const __hip_bfloat16* __restrict__ ballf,
            const __hip_bfloat16* __restrict__ aS,
            const int* __restrict__ idxp,
            const float* __restrict__ sc1, const float* __restrict__ sh1,
            float* __restrict__ bn1_slots,
            float* __restrict__ sout, float* __restrict__ bn2_slots) {
    __shared__ float bn_s[256];
    __shared__ float sc_s[128], sh_s[128];

    const int t = threadIdx.x;
    const int w = t >> 6, l = t & 63;
    const int lo = l & 15, hi = l >> 4;
    const bool real = lo < MNBR;
    const int elo = real ? lo : 0;           // clamp pad lanes in-bounds
    const int atom0 = blockIdx.x * 16 + w * 4;
    const short* xbS = (const short*)xb;
    const short* nbS = (const short*)nbrb;
    const short* aSS = (const short*)aS;
    const short* bb  = (const short*)ballf;

    bn_s[t] = 0.f;
    if (APPLY && t < 128) { sc_s[t] = sc1[t]; sh_s[t] = sh1[t]; }
    __syncthreads();

    const bf16x8 zz = {0, 0, 0, 0, 0, 0, 0, 0};
    const int off1 = (hi < 2) ? (32 + hi * 8) : 0;   // slice-1 source (k=32..47) or dummy

#pragma unroll 1
    for (int pr = 0; pr < 2; ++pr) {
        const int a0 = atom0 + pr * 2;
        const int a1 = a0 + 1;
        const int j0 = idxp[(long)a0 * MNBR + elo];
        const int j1 = idxp[(long)a1 * MNBR + elo];
        const short* xj0 = xbS + (long)j0 * FDIM + hi * 8;
        const short* xj1 = xbS + (long)j1 * FDIM + hi * 8;
        const short* nb0 = nbS + ((long)a0 * MNBR + elo) * KP48;
        const short* nb1 = nbS + ((long)a1 * MNBR + elo) * KP48;
        bf16x8 A00 = *(const bf16x8*)(xj0);
        bf16x8 A01 = *(const bf16x8*)(xj0 + 32);
        bf16x8 A02 = *(const bf16x8*)(nb0 + hi * 8);
        bf16x8 n03 = *(const bf16x8*)(nb0 + off1);
        bf16x8 A03 = (hi < 2) ? n03 : zz;            // k=48..63 are zero
        bf16x8 A10 = *(const bf16x8*)(xj1);
        bf16x8 A11 = *(const bf16x8*)(xj1 + 32);
        bf16x8 A12 = *(const bf16x8*)(nb1 + hi * 8);
        bf16x8 n13 = *(const bf16x8*)(nb1 + off1);
        bf16x8 A13 = (hi < 2) ? n13 : zz;

        if (APPLY == 0) {
#pragma unroll 2
            for (int P = 0; P < 8; ++P) {
                const short* bp = bb + P * 2048 + l * 8;
                bf16x8 B0 = *(const bf16x8*)(bp);
                bf16x8 B1 = *(const bf16x8*)(bp + 512);
                bf16x8 B2 = *(const bf16x8*)(bp + 1024);
                bf16x8 B3 = *(const bf16x8*)(bp + 1536);
                float a0v = bf2f((unsigned short)aSS[(long)a0 * C2 + P * 16 + lo]);
                float a1v = bf2f((unsigned short)aSS[(long)a1 * C2 + P * 16 + lo]);
                f32x4 z0 = {0.f, 0.f, 0.f, 0.f}, z1 = {0.f, 0.f, 0.f, 0.f};
                z0 = __builtin_amdgcn_mfma_f32_16x16x32_bf16(A00, B0, z0, 0, 0, 0);
                z1 = __builtin_amdgcn_mfma_f32_16x16x32_bf16(A10, B0, z1, 0, 0, 0);
                z0 = __builtin_amdgcn_mfma_f32_16x16x32_bf16(A01, B1, z0, 0, 0, 0);
                z1 = __builtin_amdgcn_mfma_f32_16x16x32_bf16(A11, B1, z1, 0, 0, 0);
                z0 = __builtin_amdgcn_mfma_f32_16x16x32_bf16(A02, B2, z0, 0, 0, 0);
                z1 = __builtin_amdgcn_mfma_f32_16x16x32_bf16(A12, B2, z1, 0, 0, 0);
                z0 = __builtin_amdgcn_mfma_f32_16x16x32_bf16(A03, B3, z0, 0, 0, 0);
                z1 = __builtin_amdgcn_mfma_f32_16x16x32_bf16(A13, B3, z1, 0, 0, 0);
#pragma unroll
                for (int g = 0; g < 2; ++g) {
                    f32x4 z = g ? z1 : z0;
                    float av = g ? a1v : a0v;
                    float sz = z[0] + z[1] + z[2] + z[3];
                    float szz = z[0] * z[0] + z[1] * z[1] + z[2] * z[2] + z[3] * z[3];
                    float s1 = sz + 4.f * av;
                    float s2 = szz + 2.f * av * sz + 4.f * av * av;
                    if (hi == 3) { s1 = 0.f; s2 = 0.f; }   // mask pad rows
                    s1 += __shfl_xor(s1, 16); s2 += __shfl_xor(s2, 16);
                    s1 += __shfl_xor(s1, 32); s2 += __shfl_xor(s2, 32);
                    if (hi == 0) {
                        atomicAdd(&bn_s[P * 16 + lo], s1);
                        atomicAdd(&bn_s[128 + P * 16 + lo], s2);
                    }
                }
            }
        } else {
#pragma unroll 1
            for (int P = 0; P < 4; ++P) {
                const short* bpf = bb + P * 2048 + l * 8;
                const short* bpc = bb + (P + 4) * 2048 + l * 8;
                bf16x8 Bf0 = *(const bf16x8*)(bpf);
                bf16x8 Bf1 = *(const bf16x8*)(bpf + 512);
                bf16x8 Bf2 = *(const bf16x8*)(bpf + 1024);
                bf16x8 Bf3 = *(const bf16x8*)(bpf + 1536);
                bf16x8 Bc0 = *(const bf16x8*)(bpc);
                bf16x8 Bc1 = *(const bf16x8*)(bpc + 512);
                bf16x8 Bc2 = *(const bf16x8*)(bpc + 1024);
                bf16x8 Bc3 = *(const bf16x8*)(bpc + 1536);
                const int c = P * 16 + lo;
                const float s_f = sc_s[c], h_f = sh_s[c];
                const float s_c = sc_s[64 + c], h_c = sh_s[64 + c];
                float hv0f = bf2f((unsigned short)aSS[(long)a0 * C2 + c]) * s_f + h_f;
                float hv0c = bf2f((unsigned short)aSS[(long)a0 * C2 + 64 + c]) * s_c + h_c;
                float hv1f = bf2f((unsigned short)aSS[(long)a1 * C2 + c]) * s_f + h_f;
                float hv1c = bf2f((unsigned short)aSS[(long)a1 * C2 + 64 + c]) * s_c + h_c;
                f32x4 zf0 = {0.f, 0.f, 0.f, 0.f}, zc0 = {0.f, 0.f, 0.f, 0.f};
                f32x4 zf1 = {0.f, 0.f, 0.f, 0.f}, zc1 = {0.f, 0.f, 0.f, 0.f};
                zf0 = __builtin_amdgcn_mfma_f32_16x16x32_bf16(A00, Bf0, zf0, 0, 0, 0);
                zc0 = __builtin_amdgcn_mfma_f32_16x16x32_bf16(A00, Bc0, zc0, 0, 0, 0);
                zf1 = __builtin_amdgcn_mfma_f32_16x16x32_bf16(A10, Bf0, zf1, 0, 0, 0);
                zc1 = __builtin_amdgcn_mfma_f32_16x16x32_bf16(A10, Bc0, zc1, 0, 0, 0);
                zf0 = __builtin_amdgcn_mfma_f32_16x16x32_bf16(A01, Bf1, zf0, 0, 0, 0);
                zc0 = __builtin_amdgcn_mfma_f32_16x16x32_bf16(A01, Bc1, zc0, 0, 0, 0);
                zf1 = __builtin_amdgcn_mfma_f32_16x16x32_bf16(A11, Bf1, zf1, 0, 0, 0);
                zc1 = __builtin_amdgcn_mfma_f32_16x16x32_bf16(A11, Bc1, zc1, 0, 0, 0);
                zf0 = __builtin_amdgcn_mfma_f32_16x16x32_bf16(A02, Bf2, zf0, 0, 0, 0);
                zc0 = __builtin_amdgcn_mfma_f32_16x16x32_bf16(A02, Bc2, zc0, 0, 0, 0);
                zf1 = __builtin_amdgcn_mfma_f32_16x16x32_bf16(A12, Bf2, zf1, 0, 0, 0);
                zc1 = __builtin_amdgcn_mfma_f32_16x16x32_bf16(A12, Bc2, zc1, 0, 0, 0);
                zf0 = __builtin_amdgcn_mfma_f32_16x16x32_bf16(A03, Bf3, zf0, 0, 0, 0);
                zc0 = __builtin_amdgcn_mfma_f32_16x16x32_bf16(A03, Bc3, zc0, 0, 0, 0);
                zf1 = __builtin_amdgcn_mfma_f32_16x16x32_bf16(A13, Bf3, zf1, 0, 0, 0);
                zc1 = __builtin_amdgcn_mfma_f32_16x16x32_bf16(A13, Bc3, zc1, 0, 0, 0);
#pragma unroll
                for (int g = 0; g < 2; ++g) {
                    f32x4 zf = g ? zf1 : zf0;
                    f32x4 zc = g ? zc1 : zc0;
                    float hvf = g ? hv1f : hv0f;
                    float hvc = g ? hv1c : hv0c;
                    float pvsum = 0.f;
#pragma unroll
                    for (int qq = 0; qq < 4; ++qq) {
                        float zfh = zf[qq] * s_f + hvf;
                        float zch = zc[qq] * s_c + hvc;
                        float filt = 1.f / (1.f + __expf(-zfh));
                        pvsum += filt * softplus_f(zch);
                    }
                    if (hi == 3) pvsum = 0.f;   // mask pad rows
                    pvsum += __shfl_xor(pvsum, 16);
                    pvsum += __shfl_xor(pvsum, 32);
                    if (hi == 0) {
                        sout[(long)(g ? a1 : a0) * FDIM + c] = pvsum;
                        atomicAdd(&bn_s[c], pvsum);
                        atomicAdd(&bn_s[64 + c], pvsum * pvsum);
                    }
                }
            }
        }
    }

    __syncthreads();
    if (APPLY == 0) {
        atomicAdd(&bn1_slots[(blockIdx.x & 63) * 256 + t], bn_s[t]);
    } else {
        if (t < 128)
            atomicAdd(&bn2_slots[(blockIdx.x & 63) * 128 + t], bn_s[t]);
    }
}

// reduce 64 slots -> scale/shift; zero slots for next layer.
// Linear bias is a no-op under training-mode BN -> no bias anywhere.
__global__ void k_bnfin(float* __restrict__ slots, const float* __restrict__ gamma,
                        const float* __restrict__ beta,
                        float* __restrict__ scale, float* __restrict__ shift,
                        float inv_cnt, int nc) {
    int c = threadIdx.x;
    if (c >= nc) return;
    float s1 = 0.f, s2 = 0.f;
    for (int s = 0; s < 64; ++s) {
        s1 += slots[s * 2 * nc + c];
        s2 += slots[s * 2 * nc + nc + c];
    }
    for (int s = 0; s < 64; ++s) {
        slots[s * 2 * nc + c] = 0.f;
        slots[s * 2 * nc + nc + c] = 0.f;
    }
    float mu = s1 * inv_cnt;
    float var = fmaxf(s2 * inv_cnt - mu * mu, 0.f);
    float sc = gamma[c] * rsqrtf(var + EPSBN);
    scale[c] = sc;
    shift[c] = beta[c] - mu * sc;
}

// x = softplus(x + bn2(s)); also refresh xb
__global__ void k_x(float* __restrict__ x, __hip_bfloat16* __restrict__ xb,
                    const float* __restrict__ s,
                    const float* __restrict__ scale2, const float* __restrict__ shift2) {
    long i = (long)blockIdx.x * 256 + threadIdx.x;
    if (i >= (long)NATOM * FDIM) return;
    int c = (int)(i & 63);
    float v = softplus_f(x[i] + s[i] * scale2[c] + shift2[c]);
    x[i] = v;
    xb[i] = __float2bfloat16(v);
}

__global__ void k_pool(const float* __restrict__ x, const int* __restrict__ seg,
                       float* __restrict__ cry, float* __restrict__ cnt) {
    long i = (long)blockIdx.x * 256 + threadIdx.x;
    if (i >= (long)NATOM * FDIM) return;
    int n = (int)(i >> 6), c = (int)(i & 63);
    int cr = seg[n];
    atomicAdd(&cry[(long)cr * FDIM + c], x[i]);
    if (c == 0) atomicAdd(&cnt[cr], 1.f);
}

__global__ __launch_bounds__(256)
void k_head(const float* __restrict__ cry, const float* __restrict__ cnt,
            const float* __restrict__ fw, const float* __restrict__ fb,
            const float* __restrict__ hw, const float* __restrict__ hb,
            const float* __restrict__ ow, const float* __restrict__ ob,
            float* __restrict__ out) {
    __shared__ float cs[64], h1[128], red[256];
    int t = threadIdx.x, cr = blockIdx.x;
    if (t < 64) cs[t] = cry[(long)cr * 64 + t] / fmaxf(cnt[cr], 1.f);
    __syncthreads();
    if (t < 128) {
        float a = fb[t];
        for (int k = 0; k < 64; ++k) a += cs[k] * fw[k * 128 + t];
        h1[t] = fmaxf(a, 0.f);
    }
    __syncthreads();
    float a = hb[t];
    for (int k = 0; k < 128; ++k) a += h1[k] * hw[k * 256 + t];
    red[t] = a * ow[t];
    __syncthreads();
    for (int off = 128; off > 0; off >>= 1) {
        if (t < off) red[t] += red[t + off];
        __syncthreads();
    }
    if (t == 0) out[cr] = red[0] + ob[0];
}

extern "C" void kernel_launch(void* const* d_in, const int* in_sizes, int n_in,
                              void* d_out, int out_size, void* d_ws, size_t ws_size,
                              hipStream_t stream) {
    const float* atom_fea = (const float*)d_in[0];
    const float* nbr_fea  = (const float*)d_in[1];
    const int*   nbr_idx  = (const int*)d_in[2];
    const int*   seg      = (const int*)d_in[3];
    const float* emb_w    = (const float*)d_in[4];
    const float* emb_b    = (const float*)d_in[5];
    const float* conv_w   = (const float*)d_in[6];
    const float* bn1_g    = (const float*)d_in[8];
    const float* bn1_b    = (const float*)d_in[9];
    const float* bn2_g    = (const float*)d_in[10];
    const float* bn2_b    = (const float*)d_in[11];
    const float* fc_w     = (const float*)d_in[12];
    const float* fc_b     = (const float*)d_in[13];
    const float* head_w   = (const float*)d_in[14];
    const float* head_b   = (const float*)d_in[15];
    const float* out_w    = (const float*)d_in[16];
    const float* out_b    = (const float*)d_in[17];
    float* out = (float*)d_out;

    float* ws = (float*)d_ws;
    float* x = ws + X_OFF;
    __hip_bfloat16* xb     = (__hip_bfloat16*)(ws + XB_OFF);
    float* s = ws + S_OFF;
    __hip_bfloat16* nbrb   = (__hip_bfloat16*)(ws + NBRB_OFF);
    __hip_bfloat16* aS     = (__hip_bfloat16*)(ws + AS_OFF);
    __hip_bfloat16* ballf  = (__hip_bfloat16*)(ws + BALL_OFF);
    __hip_bfloat16* ballfS = (__hip_bfloat16*)(ws + BALLS_OFF);
    float* bn1s = ws + BN1S_OFF;
    float* bn2s = ws + BN2S_OFF;
    float* sc1 = ws + SC1_OFF;
    float* sh1 = ws + SH1_OFF;
    float* sc2 = ws + SC2_OFF;
    float* sh2 = ws + SH2_OFF;
    float* cry = ws + CRY_OFF;
    float* cnt = ws + CNT_OFF;

    k_zero<<<(int)((ZERO_CNT + 255) / 256), 256, 0, stream>>>(ws + ZERO_OFF, ZERO_CNT);
    k_nbrcvt<<<(int)(((long)NEDGE * 6 + 255) / 256), 256, 0, stream>>>(nbr_fea, nbrb);
    k_embed<<<NATOM / 16, 256, 0, stream>>>(atom_fea, emb_w, emb_b, x, xb);

    for (int i = 0; i < 3; ++i) {
        const float* cw = conv_w + (long)i * 169 * C2;
        k_bcvt<<<96, 256, 0, stream>>>(cw, ballf, ballfS);
        k_lin<<<1563, 256, 0, stream>>>(xb, ballfS, aS);
        k_edge<0><<<NATOM / 16, 256, 0, stream>>>(xb, nbrb, ballf, aS, nbr_idx,
                                                  nullptr, nullptr, bn1s, nullptr, nullptr);
        k_bnfin<<<1, 128, 0, stream>>>(bn1s, bn1_g + i * C2, bn1_b + i * C2,
                                       sc1, sh1, 1.f / 1200000.f, 128);
        k_edge<1><<<NATOM / 16, 256, 0, stream>>>(xb, nbrb, ballf, aS, nbr_idx,
                                                  sc1, sh1, nullptr, s, bn2s);
        k_bnfin<<<1, 64, 0, stream>>>(bn2s, bn2_g + i * 64, bn2_b + i * 64,
                                      sc2, sh2, 1e-5f, 64);
        k_x<<<(NATOM * FDIM) / 256, 256, 0, stream>>>(x, xb, s, sc2, sh2);
    }

    k_pool<<<(NATOM * FDIM) / 256, 256, 0, stream>>>(x, seg, cry, cnt);
    k_head<<<2000, 256, 0, stream>>>(cry, cnt, fc_w, fc_b, head_w, head_b, out_w, out_b, out);
}